// Round 7
// baseline (395.601 us; speedup 1.0000x reference)
//
#include <hip/hip_runtime.h>

// Problem constants (GNNRNNModel_18270790877883)
constexpr int NN = 20000;   // nodes
constexpr int NE = 320000;  // edges
constexpr int TT = 12;      // timesteps
constexpr int CIN = 128;    // in channels
constexpr int GH = 64;      // gnn hidden
constexpr int RH = 128;     // rnn hidden
constexpr int TOTAL = TT * NN;  // 240000

typedef __attribute__((ext_vector_type(8))) short short8;
typedef __attribute__((ext_vector_type(4))) float f32x4;

__device__ __forceinline__ float rcp_fast(float x) { return __builtin_amdgcn_rcpf(x); }
__device__ __forceinline__ float sigf(float x) { return rcp_fast(1.0f + __expf(-x)); }
__device__ __forceinline__ float tanh_fast(float x) { return 1.0f - 2.0f * rcp_fast(__expf(2.0f * x) + 1.0f); }

__device__ __forceinline__ unsigned short f2b_rn(float x) {
    union { float f; unsigned int u; } v; v.f = x;
    unsigned int r = v.u + 0x7FFFu + ((v.u >> 16) & 1u);
    return (unsigned short)(r >> 16);
}
__device__ __forceinline__ float b2f(unsigned short b) {
    union { unsigned int u; float f; } v; v.u = ((unsigned int)b) << 16;
    return v.f;
}
__device__ __forceinline__ float b2f_lo(unsigned int u) {
    union { unsigned int u; float f; } v; v.u = u << 16;
    return v.f;
}
__device__ __forceinline__ float b2f_hi(unsigned int u) {
    union { unsigned int u; float f; } v; v.u = u & 0xFFFF0000u;
    return v.f;
}

__device__ __forceinline__ void gload_lds16(const void* g, void* l) {
    __builtin_amdgcn_global_load_lds((const __attribute__((address_space(1))) void*)g,
                                     (__attribute__((address_space(3))) void*)l, 16, 0, 0);
}

// ---------------- graph preprocessing ----------------

__global__ __launch_bounds__(256) void degree_kernel(const int* __restrict__ dst, int* __restrict__ deg) {
    int e = blockIdx.x * blockDim.x + threadIdx.x;
    if (e < NE) atomicAdd(&deg[dst[e]], 1);
}

__global__ __launch_bounds__(256) void dinv_kernel(const int* __restrict__ deg, float* __restrict__ dinv) {
    int n = blockIdx.x * blockDim.x + threadIdx.x;
    if (n < NN) dinv[n] = rsqrtf((float)deg[n] + 1.0f);  // +1 self loop
}

__global__ __launch_bounds__(1024) void scan_kernel(const int* __restrict__ deg, int* __restrict__ row_ptr,
                                                    int* __restrict__ cursor) {
    __shared__ int sums[1024];
    int t = threadIdx.x;
    const int per = (NN + 1023) / 1024;
    int start = t * per;
    int end = min(start + per, NN);
    int s = 0;
    for (int i = start; i < end; ++i) s += deg[i];
    sums[t] = s;
    __syncthreads();
    for (int off = 1; off < 1024; off <<= 1) {
        int v = (t >= off) ? sums[t - off] : 0;
        __syncthreads();
        sums[t] += v;
        __syncthreads();
    }
    int run = (t == 0) ? 0 : sums[t - 1];
    for (int i = start; i < end; ++i) {
        row_ptr[i] = run;
        cursor[i] = run;
        run += deg[i];
    }
    if (t == 1023) row_ptr[NN] = sums[1023];
}

__global__ __launch_bounds__(256) void scatter_kernel(const int* __restrict__ src, const int* __restrict__ dst,
                                                      const float* __restrict__ dinv, int* __restrict__ cursor,
                                                      int* __restrict__ csr_src, float* __restrict__ csr_norm) {
    int e = blockIdx.x * blockDim.x + threadIdx.x;
    if (e >= NE) return;
    int d = dst[e], s = src[e];
    int pos = atomicAdd(&cursor[d], 1);
    csr_src[pos] = s;
    csr_norm[pos] = dinv[s] * dinv[d];
}

// ---------------- weight prep (bf16, XOR-swizzled granule layout) ----------------

__global__ __launch_bounds__(256) void wprep_lstm_kernel(const float* __restrict__ w_ih, const float* __restrict__ w_hh,
                                                         unsigned short* __restrict__ wp) {
    int gidx = blockIdx.x * blockDim.x + threadIdx.x;  // granule id
    if (gidx >= 6 * 512 * 4) return;
    int gs = gidx & 3;
    int col = (gidx >> 2) & 511;
    int chunk = gidx >> 11;
    int g = gs ^ ((col >> 1) & 3);
    int k0 = chunk * 32 + g * 8;
    short8 v;
#pragma unroll
    for (int j = 0; j < 8; ++j) {
        int k = k0 + j;
        float f = (k < 64) ? w_ih[col * 64 + k] : w_hh[col * 128 + (k - 64)];
        v[j] = (short)f2b_rn(f);
    }
    *reinterpret_cast<short8*>(wp + (size_t)gidx * 8) = v;
}

__global__ __launch_bounds__(256) void wprep_gcn_kernel(const float* __restrict__ gcn_w, unsigned short* __restrict__ wx) {
    int gidx = blockIdx.x * blockDim.x + threadIdx.x;
    if (gidx >= 4 * 64 * 4) return;
    int gs = gidx & 3;
    int col = (gidx >> 2) & 63;
    int chunk = gidx >> 8;
    int g = gs ^ ((col >> 1) & 3);
    int k0 = chunk * 32 + g * 8;
    short8 v;
#pragma unroll
    for (int j = 0; j < 8; ++j) v[j] = (short)f2b_rn(gcn_w[(k0 + j) * 64 + col]);
    *reinterpret_cast<short8*>(wx + (size_t)gidx * 8) = v;
}

__global__ __launch_bounds__(256) void bias_kernel(const float* __restrict__ b_ih, const float* __restrict__ b_hh,
                                                   float* __restrict__ bias) {
    int i = blockIdx.x * blockDim.x + threadIdx.x;
    if (i < 4 * RH) bias[i] = b_ih[i] + b_hh[i];
}

// ---------------- batched XW: bf16 MFMA GEMM  M=240000 K=128 N=64, bf16 out ----------------

__global__ __launch_bounds__(256) void xw_mfma_kernel(const float* __restrict__ x,          // [TOTAL,128]
                                                      const unsigned short* __restrict__ wx,
                                                      unsigned short* __restrict__ xwb) {   // [TOTAL,64] bf16
    __shared__ __align__(16) char As[4 * 4096];  // [chunk][64 rows][4 gs][16B]
    __shared__ __align__(16) char Bs[4 * 4096];  // [chunk][64 cols][4 gs][16B]
    int tid = threadIdx.x;
    int lane = tid & 63, w = tid >> 6;
    int m0 = blockIdx.x * 64;

#pragma unroll
    for (int j = 0; j < 4; ++j) {
        const unsigned short* src = wx + (size_t)(w * 4 + j) * 512 + lane * 8;
        gload_lds16(src, Bs + (w * 4 + j) * 1024);
    }
    {
        int row = tid >> 2, gs = tid & 3;
        int srow = m0 + row;
        int g = gs ^ ((row >> 1) & 3);
        const float* sp = x + (size_t)srow * CIN + g * 8;
#pragma unroll
        for (int c = 0; c < 4; ++c) {
            float4 f0 = *reinterpret_cast<const float4*>(sp + c * 32);
            float4 f1 = *reinterpret_cast<const float4*>(sp + c * 32 + 4);
            short8 v;
            v[0] = (short)f2b_rn(f0.x); v[1] = (short)f2b_rn(f0.y);
            v[2] = (short)f2b_rn(f0.z); v[3] = (short)f2b_rn(f0.w);
            v[4] = (short)f2b_rn(f1.x); v[5] = (short)f2b_rn(f1.y);
            v[6] = (short)f2b_rn(f1.z); v[7] = (short)f2b_rn(f1.w);
            *reinterpret_cast<short8*>(As + c * 4096 + row * 64 + gs * 16) = v;
        }
    }
    __syncthreads();

    f32x4 acc[4] = {};
    int rl = w * 16 + (lane & 15);
    int o = lane >> 4;
#pragma unroll
    for (int c = 0; c < 4; ++c) {
        int gsa = o ^ ((rl >> 1) & 3);
        short8 a = *reinterpret_cast<const short8*>(As + c * 4096 + rl * 64 + gsa * 16);
#pragma unroll
        for (int cn = 0; cn < 4; ++cn) {
            int col = cn * 16 + (lane & 15);
            int gsb = o ^ ((col >> 1) & 3);
            short8 b = *reinterpret_cast<const short8*>(Bs + c * 4096 + col * 64 + gsb * 16);
            acc[cn] = __builtin_amdgcn_mfma_f32_16x16x32_bf16(a, b, acc[cn], 0, 0, 0);
        }
    }
#pragma unroll
    for (int cn = 0; cn < 4; ++cn)
#pragma unroll
        for (int r = 0; r < 4; ++r) {
            int row = m0 + w * 16 + (lane >> 4) * 4 + r;
            int col = cn * 16 + (lane & 15);
            xwb[(size_t)row * GH + col] = f2b_rn(acc[cn][r]);
        }
}

// ---------------- batched GCN aggregation: wave = 2 nodes x 4 timesteps ----------------
// Indices/norms loaded+shuffled once per 4 slices; 32 gather loads in flight per 8-edge group.

__global__ __launch_bounds__(256) void gather_kernel(const unsigned short* __restrict__ xwb, const float* __restrict__ dinv,
                                                     const int* __restrict__ row_ptr, const int* __restrict__ csr_src,
                                                     const float* __restrict__ csr_norm, const float* __restrict__ gcn_b,
                                                     unsigned short* __restrict__ hs_b) {
    int t0 = blockIdx.y * 4;
    int wpair = (blockIdx.x * blockDim.x + threadIdx.x) >> 6;  // node-pair id
    int lane = threadIdx.x & 63;
    int g = lane >> 5, sl = lane & 31;
    int node = wpair * 2 + g;
    const unsigned int* s0 = (const unsigned int*)(xwb + (size_t)t0 * NN * GH);
    const unsigned int* s1 = s0 + (size_t)NN * 32;
    const unsigned int* s2 = s1 + (size_t)NN * 32;
    const unsigned int* s3 = s2 + (size_t)NN * 32;

    float dv = dinv[node];
    float b0 = gcn_b[sl * 2], b1 = gcn_b[sl * 2 + 1];
    float ax0, ay0, ax1, ay1, ax2, ay2, ax3, ay3;
    {
        unsigned int u0 = s0[(size_t)node * 32 + sl];
        unsigned int u1 = s1[(size_t)node * 32 + sl];
        unsigned int u2 = s2[(size_t)node * 32 + sl];
        unsigned int u3 = s3[(size_t)node * 32 + sl];
        float dd = dv * dv;
        ax0 = b0 + dd * b2f_lo(u0); ay0 = b1 + dd * b2f_hi(u0);
        ax1 = b0 + dd * b2f_lo(u1); ay1 = b1 + dd * b2f_hi(u1);
        ax2 = b0 + dd * b2f_lo(u2); ay2 = b1 + dd * b2f_hi(u2);
        ax3 = b0 + dd * b2f_lo(u3); ay3 = b1 + dd * b2f_hi(u3);
    }

    int e0 = row_ptr[node];
    int deg = row_ptr[node + 1] - e0;
    int degA = __shfl(deg, 0), degB = __shfl(deg, 32);
    int dmax = max(degA, degB);

    for (int base = 0; base < dmax; base += 32) {
        int cnt = min(deg - base, 32);
        bool valid = sl < cnt;
        int myidx = valid ? csr_src[e0 + base + sl] : 0;
        float mynm = valid ? csr_norm[e0 + base + sl] : 0.f;
        int c8 = (max(cnt, 0) + 7) & ~7;
        int c8o = __shfl(c8, (1 - g) << 5);
        int c8w = max(c8, c8o);
        for (int jb = 0; jb < c8w; jb += 8) {
#pragma unroll
            for (int jj = 0; jj < 8; ++jj) {
                int si = __shfl(myidx, (g << 5) + jb + jj);
                float ni = __shfl(mynm, (g << 5) + jb + jj);
                unsigned int u0 = s0[(size_t)si * 32 + sl];
                unsigned int u1 = s1[(size_t)si * 32 + sl];
                unsigned int u2 = s2[(size_t)si * 32 + sl];
                unsigned int u3 = s3[(size_t)si * 32 + sl];
                ax0 += ni * b2f_lo(u0); ay0 += ni * b2f_hi(u0);
                ax1 += ni * b2f_lo(u1); ay1 += ni * b2f_hi(u1);
                ax2 += ni * b2f_lo(u2); ay2 += ni * b2f_hi(u2);
                ax3 += ni * b2f_lo(u3); ay3 += ni * b2f_hi(u3);
            }
        }
    }
    unsigned int* ob = (unsigned int*)hs_b;
    ob[((size_t)(t0 + 0) * NN + node) * 32 + sl] = (unsigned int)f2b_rn(ax0) | ((unsigned int)f2b_rn(ay0) << 16);
    ob[((size_t)(t0 + 1) * NN + node) * 32 + sl] = (unsigned int)f2b_rn(ax1) | ((unsigned int)f2b_rn(ay1) << 16);
    ob[((size_t)(t0 + 2) * NN + node) * 32 + sl] = (unsigned int)f2b_rn(ax2) | ((unsigned int)f2b_rn(ay2) << 16);
    ob[((size_t)(t0 + 3) * NN + node) * 32 + sl] = (unsigned int)f2b_rn(ax3) | ((unsigned int)f2b_rn(ay3) << 16);
}

// ---------------- persistent LSTM: 209 blocks x 512 thr; TWO independent 48-row chains per block ----------------
// Phase pipeline: {M_B(t) || E_A(t)} bar {M_A(t+1) || E_B(t)} bar ... -> MFMA and trans/VALU
// pipes busy in every phase. B-fragments streamed from L2 per chunk (192KB image, L2-resident).

#define HS_A 0              // [2 slots][2 chunks][48 rows][4 gs][16B] = 12288
#define HS_B 12288
#define HA_A 24576          // [4 chunks][48 rows][4 gs][16B] = 12288
#define HA_B 36864
#define RED_OFF 49152       // float [8][96] = 3072
#define SMEM_BYTES 52224

__device__ __forceinline__ void stage_hs(char* smem, const unsigned short* __restrict__ hs_all,
                                         int base, int tnext, int tid) {
    int slot = tnext & 1;
#pragma unroll
    for (int jj = 0; jj < 2; ++jj) {
        int gi = jj * 512 + tid;
        if (gi < 768) {
            int chain = (gi >= 384) ? 1 : 0;
            int q = gi - chain * 384;
            int cc = (q >= 192) ? 1 : 0;
            int rem = q - cc * 192;
            int row = rem >> 2, gs = rem & 3;
            int g = gs ^ ((row >> 1) & 3);
            int grow = min(base + chain * 48 + row, NN - 1);
            const unsigned short* src = hs_all + ((size_t)tnext * NN + grow) * 64 + cc * 32 + g * 8;
            gload_lds16(src, smem + chain * 12288 + slot * 6144 + cc * 3072 + row * 64 + gs * 16);
        }
    }
}

template <int HSOFF, int HAOFF>
__device__ __forceinline__ void m_phase(f32x4 (&acc)[3][4], char* smem, int t,
                                        int colbase, int sw, int l15,
                                        const unsigned short* __restrict__ wp) {
#pragma unroll
    for (int mi = 0; mi < 3; ++mi)
#pragma unroll
        for (int g = 0; g < 4; ++g) acc[mi][g] = (f32x4){0.f, 0.f, 0.f, 0.f};
    const char* hsb = smem + HSOFF + (t & 1) * 6144;
#pragma unroll
    for (int c = 0; c < 6; ++c) {
        short8 b[4];
#pragma unroll
        for (int g = 0; g < 4; ++g)
            b[g] = *reinterpret_cast<const short8*>(wp + ((size_t)((c * 512 + g * 128 + colbase) * 4 + sw)) * 8);
        const char* abase = (c < 2) ? (hsb + c * 3072) : (smem + HAOFF + (c - 2) * 3072);
        short8 a[3];
#pragma unroll
        for (int mi = 0; mi < 3; ++mi)
            a[mi] = *reinterpret_cast<const short8*>(abase + (mi * 16 + l15) * 64 + sw * 16);
#pragma unroll
        for (int g = 0; g < 4; ++g)
#pragma unroll
            for (int mi = 0; mi < 3; ++mi)
                acc[mi][g] = __builtin_amdgcn_mfma_f32_16x16x32_bf16(a[mi], b[g], acc[mi][g], 0, 0, 0);
    }
}

template <int HAOFF, int CROW>
__device__ __forceinline__ void e_phase(f32x4 (&acc)[3][4], float (&creg)[3][4], char* smem,
                                        bool last, int w, int o, int l15,
                                        float bi, float bff, float bg, float bo, float fcw,
                                        int h_chunk, int h_g, int h_j) {
    if (!last) {
#pragma unroll
        for (int mi = 0; mi < 3; ++mi)
#pragma unroll
            for (int r = 0; r < 4; ++r) {
                float iv = sigf(acc[mi][0][r] + bi);
                float fv = sigf(acc[mi][1][r] + bff);
                float gv = tanh_fast(acc[mi][2][r] + bg);
                float ov = sigf(acc[mi][3][r] + bo);
                float cnew = fv * creg[mi][r] + iv * gv;
                creg[mi][r] = cnew;
                float hv = ov * tanh_fast(cnew);
                int row = mi * 16 + o * 4 + r;
                int gs_h = h_g ^ ((row >> 1) & 3);
                *(unsigned short*)(smem + HAOFF + h_chunk * 3072 + row * 64 + gs_h * 16 + h_j * 2) = f2b_rn(hv);
            }
    } else {
#pragma unroll
        for (int mi = 0; mi < 3; ++mi)
#pragma unroll
            for (int r = 0; r < 4; ++r) {
                float iv = sigf(acc[mi][0][r] + bi);
                float fv = sigf(acc[mi][1][r] + bff);
                float gv = tanh_fast(acc[mi][2][r] + bg);
                float ov = sigf(acc[mi][3][r] + bo);
                float cnew = fv * creg[mi][r] + iv * gv;
                float hv = ov * tanh_fast(cnew);
                float p = hv * fcw;
                p += __shfl_xor(p, 1);
                p += __shfl_xor(p, 2);
                p += __shfl_xor(p, 4);
                p += __shfl_xor(p, 8);
                if (l15 == 0) {
                    int row = mi * 16 + o * 4 + r;
                    ((float*)(smem + RED_OFF))[w * 96 + CROW + row] = p;
                }
            }
    }
}

__global__ __launch_bounds__(512, 2) void lstm_persist_kernel(const unsigned short* __restrict__ hs_all, // [TT,NN,64]
                                                              const unsigned short* __restrict__ wp,     // [6][512][4][8]
                                                              const float* __restrict__ bias,            // [512]
                                                              const float* __restrict__ fc_w,            // [128]
                                                              const float* __restrict__ fc_b,            // [1]
                                                              float* __restrict__ out) {                 // [NN]
    __shared__ __align__(16) char smem[SMEM_BYTES];
    int tid = threadIdx.x;
    int lane = tid & 63, w = tid >> 6;
    int l15 = lane & 15, o = lane >> 4;
    int base = blockIdx.x * 96;

    int sw = o ^ ((l15 >> 1) & 3);
    int colbase = w * 16 + l15;
    float bi = bias[colbase], bff = bias[128 + colbase], bg = bias[256 + colbase], bo = bias[384 + colbase];
    float fcw = fc_w[colbase];
    int h_chunk = w >> 1;
    int h_g = ((w & 1) << 1) + (l15 >> 3);
    int h_j = l15 & 7;

    // zero both h regions (HA_A..HA_B contiguous: 24576 B = 6144 ints)
#pragma unroll
    for (int i = 0; i < 12; ++i) ((int*)(smem + HA_A))[tid + i * 512] = 0;
    stage_hs(smem, hs_all, base, 0, tid);
    __syncthreads();

    f32x4 accA[3][4], accB[3][4];
    float cA[3][4] = {}, cB[3][4] = {};

    m_phase<HS_A, HA_A>(accA, smem, 0, colbase, sw, l15, wp);

#pragma unroll 1
    for (int t = 0; t < TT; ++t) {
        bool last = (t == TT - 1);
        if (!last) stage_hs(smem, hs_all, base, t + 1, tid);
        m_phase<HS_B, HA_B>(accB, smem, t, colbase, sw, l15, wp);
        e_phase<HA_A, 0>(accA, cA, smem, last, w, o, l15, bi, bff, bg, bo, fcw, h_chunk, h_g, h_j);
        __syncthreads();
        if (!last) m_phase<HS_A, HA_A>(accA, smem, t + 1, colbase, sw, l15, wp);
        e_phase<HA_B, 48>(accB, cB, smem, last, w, o, l15, bi, bff, bg, bo, fcw, h_chunk, h_g, h_j);
        __syncthreads();
    }

    if (tid < 96) {
        const float* red = (const float*)(smem + RED_OFF);
        float s = 0.f;
#pragma unroll
        for (int w8 = 0; w8 < 8; ++w8) s += red[w8 * 96 + tid];
        if (base + tid < NN) out[base + tid] = s + fc_b[0];
    }
}

// ---------------- host ----------------

extern "C" void kernel_launch(void* const* d_in, const int* in_sizes, int n_in,
                              void* d_out, int out_size, void* d_ws, size_t ws_size,
                              hipStream_t stream) {
    const float* x_seq = (const float*)d_in[0];
    const int* edge = (const int*)d_in[1];
    const float* gcn_w = (const float*)d_in[2];
    const float* gcn_b = (const float*)d_in[3];
    const float* w_ih = (const float*)d_in[4];
    const float* w_hh = (const float*)d_in[5];
    const float* b_ih = (const float*)d_in[6];
    const float* b_hh = (const float*)d_in[7];
    const float* fc_w = (const float*)d_in[8];
    const float* fc_b = (const float*)d_in[9];
    float* out = (float*)d_out;

    char* w = (char*)d_ws;
    auto carve = [&](size_t bytes) {
        void* p = (void*)w;
        w += (bytes + 255) & ~(size_t)255;
        return p;
    };
    float* dinv = (float*)carve(NN * 4);
    int* deg = (int*)carve(NN * 4);
    int* row_ptr = (int*)carve((NN + 1) * 4);
    int* cursor = (int*)carve(NN * 4);
    int* csr_src = (int*)carve(NE * 4);
    float* csr_norm = (float*)carve(NE * 4);
    unsigned short* xwb = (unsigned short*)carve((size_t)TOTAL * GH * 2);
    unsigned short* hs_b = (unsigned short*)carve((size_t)TOTAL * GH * 2);
    unsigned short* wp = (unsigned short*)carve((size_t)6 * 512 * 4 * 8 * 2);
    unsigned short* wx = (unsigned short*)carve((size_t)4 * 64 * 4 * 8 * 2);
    float* bias = (float*)carve(512 * 4);

    hipMemsetAsync(deg, 0, NN * 4, stream);

    const int* e_src = edge;
    const int* e_dst = edge + NE;

    degree_kernel<<<(NE + 255) / 256, 256, 0, stream>>>(e_dst, deg);
    dinv_kernel<<<(NN + 255) / 256, 256, 0, stream>>>(deg, dinv);
    scan_kernel<<<1, 1024, 0, stream>>>(deg, row_ptr, cursor);
    scatter_kernel<<<(NE + 255) / 256, 256, 0, stream>>>(e_src, e_dst, dinv, cursor, csr_src, csr_norm);

    wprep_lstm_kernel<<<(6 * 512 * 4 + 255) / 256, 256, 0, stream>>>(w_ih, w_hh, wp);
    wprep_gcn_kernel<<<(4 * 64 * 4 + 255) / 256, 256, 0, stream>>>(gcn_w, wx);
    bias_kernel<<<2, 256, 0, stream>>>(b_ih, b_hh, bias);

    xw_mfma_kernel<<<TOTAL / 64, 256, 0, stream>>>(x_seq, wx, xwb);
    dim3 ggrid(NN / 2 / 4, TT / 4);
    gather_kernel<<<ggrid, 256, 0, stream>>>(xwb, dinv, row_ptr, csr_src, csr_norm, gcn_b, hs_b);
    lstm_persist_kernel<<<(NN + 95) / 96, 512, 0, stream>>>(hs_b, wp, bias, fc_w, fc_b, out);
}

// Round 8
// 230.723 us; speedup vs baseline: 1.7146x; 1.7146x over previous
//
#include <hip/hip_runtime.h>

// Problem constants (GNNRNNModel_18270790877883)
constexpr int NN = 20000;   // nodes
constexpr int NE = 320000;  // edges
constexpr int TT = 12;      // timesteps
constexpr int CIN = 128;    // in channels
constexpr int GH = 64;      // gnn hidden
constexpr int RH = 128;     // rnn hidden
constexpr int TOTAL = TT * NN;  // 240000

typedef __attribute__((ext_vector_type(8))) short short8;
typedef __attribute__((ext_vector_type(4))) float f32x4;

__device__ __forceinline__ float rcp_fast(float x) { return __builtin_amdgcn_rcpf(x); }
__device__ __forceinline__ float sigf(float x) { return rcp_fast(1.0f + __expf(-x)); }
__device__ __forceinline__ float tanh_fast(float x) { return 1.0f - 2.0f * rcp_fast(__expf(2.0f * x) + 1.0f); }

__device__ __forceinline__ unsigned short f2b_rn(float x) {
    union { float f; unsigned int u; } v; v.f = x;
    unsigned int r = v.u + 0x7FFFu + ((v.u >> 16) & 1u);
    return (unsigned short)(r >> 16);
}
__device__ __forceinline__ float b2f(unsigned short b) {
    union { unsigned int u; float f; } v; v.u = ((unsigned int)b) << 16;
    return v.f;
}
__device__ __forceinline__ float b2f_lo(unsigned int u) {
    union { unsigned int u; float f; } v; v.u = u << 16;
    return v.f;
}
__device__ __forceinline__ float b2f_hi(unsigned int u) {
    union { unsigned int u; float f; } v; v.u = u & 0xFFFF0000u;
    return v.f;
}

__device__ __forceinline__ void gload_lds16(const void* g, void* l) {
    __builtin_amdgcn_global_load_lds((const __attribute__((address_space(1))) void*)g,
                                     (__attribute__((address_space(3))) void*)l, 16, 0, 0);
}

// ---------------- graph preprocessing ----------------

__global__ __launch_bounds__(256) void degree_kernel(const int* __restrict__ dst, int* __restrict__ deg) {
    int e = blockIdx.x * blockDim.x + threadIdx.x;
    if (e < NE) atomicAdd(&deg[dst[e]], 1);
}

__global__ __launch_bounds__(256) void dinv_kernel(const int* __restrict__ deg, float* __restrict__ dinv) {
    int n = blockIdx.x * blockDim.x + threadIdx.x;
    if (n < NN) dinv[n] = rsqrtf((float)deg[n] + 1.0f);  // +1 self loop
}

__global__ __launch_bounds__(1024) void scan_kernel(const int* __restrict__ deg, int* __restrict__ row_ptr,
                                                    int* __restrict__ cursor) {
    __shared__ int sums[1024];
    int t = threadIdx.x;
    const int per = (NN + 1023) / 1024;
    int start = t * per;
    int end = min(start + per, NN);
    int s = 0;
    for (int i = start; i < end; ++i) s += deg[i];
    sums[t] = s;
    __syncthreads();
    for (int off = 1; off < 1024; off <<= 1) {
        int v = (t >= off) ? sums[t - off] : 0;
        __syncthreads();
        sums[t] += v;
        __syncthreads();
    }
    int run = (t == 0) ? 0 : sums[t - 1];
    for (int i = start; i < end; ++i) {
        row_ptr[i] = run;
        cursor[i] = run;
        run += deg[i];
    }
    if (t == 1023) row_ptr[NN] = sums[1023];
}

__global__ __launch_bounds__(256) void scatter_kernel(const int* __restrict__ src, const int* __restrict__ dst,
                                                      const float* __restrict__ dinv, int* __restrict__ cursor,
                                                      int* __restrict__ csr_src, float* __restrict__ csr_norm) {
    int e = blockIdx.x * blockDim.x + threadIdx.x;
    if (e >= NE) return;
    int d = dst[e], s = src[e];
    int pos = atomicAdd(&cursor[d], 1);
    csr_src[pos] = s;
    csr_norm[pos] = dinv[s] * dinv[d];
}

// ---------------- weight prep (bf16, XOR-swizzled granule layout) ----------------

__global__ __launch_bounds__(256) void wprep_lstm_kernel(const float* __restrict__ w_ih, const float* __restrict__ w_hh,
                                                         unsigned short* __restrict__ wp) {
    int gidx = blockIdx.x * blockDim.x + threadIdx.x;  // granule id
    if (gidx >= 6 * 512 * 4) return;
    int gs = gidx & 3;
    int col = (gidx >> 2) & 511;
    int chunk = gidx >> 11;
    int g = gs ^ ((col >> 1) & 3);
    int k0 = chunk * 32 + g * 8;
    short8 v;
#pragma unroll
    for (int j = 0; j < 8; ++j) {
        int k = k0 + j;
        float f = (k < 64) ? w_ih[col * 64 + k] : w_hh[col * 128 + (k - 64)];
        v[j] = (short)f2b_rn(f);
    }
    *reinterpret_cast<short8*>(wp + (size_t)gidx * 8) = v;
}

__global__ __launch_bounds__(256) void wprep_gcn_kernel(const float* __restrict__ gcn_w, unsigned short* __restrict__ wx) {
    int gidx = blockIdx.x * blockDim.x + threadIdx.x;
    if (gidx >= 4 * 64 * 4) return;
    int gs = gidx & 3;
    int col = (gidx >> 2) & 63;
    int chunk = gidx >> 8;
    int g = gs ^ ((col >> 1) & 3);
    int k0 = chunk * 32 + g * 8;
    short8 v;
#pragma unroll
    for (int j = 0; j < 8; ++j) v[j] = (short)f2b_rn(gcn_w[(k0 + j) * 64 + col]);
    *reinterpret_cast<short8*>(wx + (size_t)gidx * 8) = v;
}

__global__ __launch_bounds__(256) void bias_kernel(const float* __restrict__ b_ih, const float* __restrict__ b_hh,
                                                   float* __restrict__ bias) {
    int i = blockIdx.x * blockDim.x + threadIdx.x;
    if (i < 4 * RH) bias[i] = b_ih[i] + b_hh[i];
}

// ---------------- batched XW: bf16 MFMA GEMM  M=240000 K=128 N=64, bf16 out ----------------

__global__ __launch_bounds__(256) void xw_mfma_kernel(const float* __restrict__ x,          // [TOTAL,128]
                                                      const unsigned short* __restrict__ wx,
                                                      unsigned short* __restrict__ xwb) {   // [TOTAL,64] bf16
    __shared__ __align__(16) char As[4 * 4096];  // [chunk][64 rows][4 gs][16B]
    __shared__ __align__(16) char Bs[4 * 4096];  // [chunk][64 cols][4 gs][16B]
    int tid = threadIdx.x;
    int lane = tid & 63, w = tid >> 6;
    int m0 = blockIdx.x * 64;

#pragma unroll
    for (int j = 0; j < 4; ++j) {
        const unsigned short* src = wx + (size_t)(w * 4 + j) * 512 + lane * 8;
        gload_lds16(src, Bs + (w * 4 + j) * 1024);
    }
    {
        int row = tid >> 2, gs = tid & 3;
        int srow = m0 + row;
        int g = gs ^ ((row >> 1) & 3);
        const float* sp = x + (size_t)srow * CIN + g * 8;
#pragma unroll
        for (int c = 0; c < 4; ++c) {
            float4 f0 = *reinterpret_cast<const float4*>(sp + c * 32);
            float4 f1 = *reinterpret_cast<const float4*>(sp + c * 32 + 4);
            short8 v;
            v[0] = (short)f2b_rn(f0.x); v[1] = (short)f2b_rn(f0.y);
            v[2] = (short)f2b_rn(f0.z); v[3] = (short)f2b_rn(f0.w);
            v[4] = (short)f2b_rn(f1.x); v[5] = (short)f2b_rn(f1.y);
            v[6] = (short)f2b_rn(f1.z); v[7] = (short)f2b_rn(f1.w);
            *reinterpret_cast<short8*>(As + c * 4096 + row * 64 + gs * 16) = v;
        }
    }
    __syncthreads();

    f32x4 acc[4] = {};
    int rl = w * 16 + (lane & 15);
    int o = lane >> 4;
#pragma unroll
    for (int c = 0; c < 4; ++c) {
        int gsa = o ^ ((rl >> 1) & 3);
        short8 a = *reinterpret_cast<const short8*>(As + c * 4096 + rl * 64 + gsa * 16);
#pragma unroll
        for (int cn = 0; cn < 4; ++cn) {
            int col = cn * 16 + (lane & 15);
            int gsb = o ^ ((col >> 1) & 3);
            short8 b = *reinterpret_cast<const short8*>(Bs + c * 4096 + col * 64 + gsb * 16);
            acc[cn] = __builtin_amdgcn_mfma_f32_16x16x32_bf16(a, b, acc[cn], 0, 0, 0);
        }
    }
#pragma unroll
    for (int cn = 0; cn < 4; ++cn)
#pragma unroll
        for (int r = 0; r < 4; ++r) {
            int row = m0 + w * 16 + (lane >> 4) * 4 + r;
            int col = cn * 16 + (lane & 15);
            xwb[(size_t)row * GH + col] = f2b_rn(acc[cn][r]);
        }
}

// ---------------- batched GCN aggregation: wave = 2 nodes x 2 timesteps (R6 known-good) ----------------

__global__ __launch_bounds__(256) void gather_kernel(const unsigned short* __restrict__ xwb, const float* __restrict__ dinv,
                                                     const int* __restrict__ row_ptr, const int* __restrict__ csr_src,
                                                     const float* __restrict__ csr_norm, const float* __restrict__ gcn_b,
                                                     unsigned short* __restrict__ hs_b) {
    int t0 = blockIdx.y * 2;
    int wpair = (blockIdx.x * blockDim.x + threadIdx.x) >> 6;  // node-pair id (0..9999)
    int lane = threadIdx.x & 63;
    int g = lane >> 5, sl = lane & 31;
    int node = wpair * 2 + g;
    const unsigned int* sl0 = (const unsigned int*)(xwb + (size_t)t0 * NN * GH);
    const unsigned int* sl1 = sl0 + (size_t)NN * 32;

    float dv = dinv[node];
    float b0 = gcn_b[sl * 2], b1 = gcn_b[sl * 2 + 1];
    unsigned int u0 = sl0[(size_t)node * 32 + sl];
    unsigned int u1 = sl1[(size_t)node * 32 + sl];
    float a0x = b0 + dv * dv * b2f_lo(u0);
    float a0y = b1 + dv * dv * b2f_hi(u0);
    float a1x = b0 + dv * dv * b2f_lo(u1);
    float a1y = b1 + dv * dv * b2f_hi(u1);

    int e0 = row_ptr[node];
    int deg = row_ptr[node + 1] - e0;
    int degA = __shfl(deg, 0), degB = __shfl(deg, 32);
    int dmax = max(degA, degB);

    for (int base = 0; base < dmax; base += 32) {
        int cnt = min(deg - base, 32);
        bool valid = sl < cnt;
        int myidx = valid ? csr_src[e0 + base + sl] : 0;
        float mynm = valid ? csr_norm[e0 + base + sl] : 0.f;
        int c8 = (max(cnt, 0) + 7) & ~7;
        int c8o = __shfl(c8, (1 - g) << 5);
        int c8w = max(c8, c8o);
        for (int j = 0; j < c8w; j += 8) {
            int s0 = __shfl(myidx, (g << 5) + j + 0), s1 = __shfl(myidx, (g << 5) + j + 1);
            int s2 = __shfl(myidx, (g << 5) + j + 2), s3 = __shfl(myidx, (g << 5) + j + 3);
            int s4 = __shfl(myidx, (g << 5) + j + 4), s5 = __shfl(myidx, (g << 5) + j + 5);
            int s6 = __shfl(myidx, (g << 5) + j + 6), s7 = __shfl(myidx, (g << 5) + j + 7);
            float n0 = __shfl(mynm, (g << 5) + j + 0), n1 = __shfl(mynm, (g << 5) + j + 1);
            float n2 = __shfl(mynm, (g << 5) + j + 2), n3 = __shfl(mynm, (g << 5) + j + 3);
            float n4 = __shfl(mynm, (g << 5) + j + 4), n5 = __shfl(mynm, (g << 5) + j + 5);
            float n6 = __shfl(mynm, (g << 5) + j + 6), n7 = __shfl(mynm, (g << 5) + j + 7);
            unsigned int p0 = sl0[(size_t)s0 * 32 + sl], q0 = sl1[(size_t)s0 * 32 + sl];
            unsigned int p1 = sl0[(size_t)s1 * 32 + sl], q1 = sl1[(size_t)s1 * 32 + sl];
            unsigned int p2 = sl0[(size_t)s2 * 32 + sl], q2 = sl1[(size_t)s2 * 32 + sl];
            unsigned int p3 = sl0[(size_t)s3 * 32 + sl], q3 = sl1[(size_t)s3 * 32 + sl];
            unsigned int p4 = sl0[(size_t)s4 * 32 + sl], q4 = sl1[(size_t)s4 * 32 + sl];
            unsigned int p5 = sl0[(size_t)s5 * 32 + sl], q5 = sl1[(size_t)s5 * 32 + sl];
            unsigned int p6 = sl0[(size_t)s6 * 32 + sl], q6 = sl1[(size_t)s6 * 32 + sl];
            unsigned int p7 = sl0[(size_t)s7 * 32 + sl], q7 = sl1[(size_t)s7 * 32 + sl];
            a0x += n0 * b2f_lo(p0); a0y += n0 * b2f_hi(p0); a1x += n0 * b2f_lo(q0); a1y += n0 * b2f_hi(q0);
            a0x += n1 * b2f_lo(p1); a0y += n1 * b2f_hi(p1); a1x += n1 * b2f_lo(q1); a1y += n1 * b2f_hi(q1);
            a0x += n2 * b2f_lo(p2); a0y += n2 * b2f_hi(p2); a1x += n2 * b2f_lo(q2); a1y += n2 * b2f_hi(q2);
            a0x += n3 * b2f_lo(p3); a0y += n3 * b2f_hi(p3); a1x += n3 * b2f_lo(q3); a1y += n3 * b2f_hi(q3);
            a0x += n4 * b2f_lo(p4); a0y += n4 * b2f_hi(p4); a1x += n4 * b2f_lo(q4); a1y += n4 * b2f_hi(q4);
            a0x += n5 * b2f_lo(p5); a0y += n5 * b2f_hi(p5); a1x += n5 * b2f_lo(q5); a1y += n5 * b2f_hi(q5);
            a0x += n6 * b2f_lo(p6); a0y += n6 * b2f_hi(p6); a1x += n6 * b2f_lo(q6); a1y += n6 * b2f_hi(q6);
            a0x += n7 * b2f_lo(p7); a0y += n7 * b2f_hi(p7); a1x += n7 * b2f_lo(q7); a1y += n7 * b2f_hi(q7);
        }
    }
    unsigned int o0 = (unsigned int)f2b_rn(a0x) | ((unsigned int)f2b_rn(a0y) << 16);
    unsigned int o1 = (unsigned int)f2b_rn(a1x) | ((unsigned int)f2b_rn(a1y) << 16);
    ((unsigned int*)hs_b)[((size_t)t0 * NN + node) * 32 + sl] = o0;
    ((unsigned int*)hs_b)[((size_t)(t0 + 1) * NN + node) * 32 + sl] = o1;
}

// ---------------- persistent LSTM: 250 blocks x 512 thr; 80 rows/block; ONE barrier per step ----------------
// h double-buffered in LDS: m_phase(t) reads slot[t&1], epilogue writes slot[(t+1)&1] -> no
// read/write hazard within a step; single __syncthreads at step end publishes h + drains hs stage.
// B fragments pinned once in registers/AGPRs (opaque-asm pin prevents rematerialization).

#define HS_OFF 0            // 2 slots x [2 chunks][80 rows][4 gs][16B] = 2 x 10240
#define HA_OFF 20480        // 2 slots x [4 chunks][80 rows][4 gs][16B] = 2 x 20480
#define RED_OFF 61440       // float [8][80] = 2560
#define SMEM_BYTES 64000

__global__ __launch_bounds__(512, 2) void lstm_persist_kernel(const unsigned short* __restrict__ hs_all, // [TT,NN,64]
                                                              const unsigned short* __restrict__ wp,     // [6][512][4][8]
                                                              const float* __restrict__ bias,            // [512]
                                                              const float* __restrict__ fc_w,            // [128]
                                                              const float* __restrict__ fc_b,            // [1]
                                                              float* __restrict__ out) {                 // [NN]
    __shared__ __align__(16) char smem[SMEM_BYTES];
    int tid = threadIdx.x;
    int lane = tid & 63, w = tid >> 6;
    int l15 = lane & 15, o = lane >> 4;
    int base = blockIdx.x * 80;

    int sw = o ^ ((l15 >> 1) & 3);       // shared swizzle for all A reads (and B prep layout)
    int colbase = w * 16 + l15;          // this thread's rh-col
    float bi = bias[colbase], bff = bias[128 + colbase], bg = bias[256 + colbase], bo = bias[384 + colbase];
    float fcw = fc_w[colbase];

    // h-write constants: k = 64 + colbase -> chunk, granule, elem
    int h_chunk = w >> 1;                          // 0..3
    int h_g = ((w & 1) << 1) + (l15 >> 3);         // granule within 32-k chunk
    int h_j = l15 & 7;                             // elem within granule

    // hoist ALL B fragments into registers (96 VGPRs/AGPRs), pinned against rematerialization
    short8 breg[6][4];
#pragma unroll
    for (int c = 0; c < 6; ++c)
#pragma unroll
        for (int g = 0; g < 4; ++g) {
            size_t goff = ((size_t)(c * 512 + g * 128 + colbase) * 4 + sw) * 8;
            breg[c][g] = *reinterpret_cast<const short8*>(wp + goff);
            asm volatile("" : "+v"(breg[c][g]));
        }

    // prologue: zero h slot 0 (t=0 reads it), stage hs[0] into slot 0
    {
#pragma unroll
        for (int i = 0; i < 10; ++i) ((int*)(smem + HA_OFF))[tid + i * 512] = 0;
#pragma unroll
        for (int j = 0; j < 2; ++j) {
            int gi = j * 512 + tid;
            if (gi < 640) {
                int cc = (gi >= 320) ? 1 : 0;
                int rem = gi - cc * 320;
                int row = rem >> 2, gs = rem & 3;
                int g = gs ^ ((row >> 1) & 3);
                const unsigned short* src = hs_all + ((size_t)(base + row)) * 64 + cc * 32 + g * 8;
                gload_lds16(src, smem + HS_OFF + gi * 16);
            }
        }
    }
    __syncthreads();  // slot-0 data (zeroed h + staged hs[0]) visible

    float c_reg[5][4] = {};
    f32x4 acc[5][4];

#pragma unroll 1
    for (int t = 0; t < TT; ++t) {
        // prefetch hs[t+1] into other slot (drains at the end-of-step barrier)
        if (t + 1 < TT) {
            char* dstb = smem + HS_OFF + ((t + 1) & 1) * 10240;
#pragma unroll
            for (int j = 0; j < 2; ++j) {
                int gi = j * 512 + tid;
                if (gi < 640) {
                    int cc = (gi >= 320) ? 1 : 0;
                    int rem = gi - cc * 320;
                    int row = rem >> 2, gs = rem & 3;
                    int g = gs ^ ((row >> 1) & 3);
                    const unsigned short* src = hs_all + ((size_t)(t + 1) * NN + base + row) * 64 + cc * 32 + g * 8;
                    gload_lds16(src, dstb + gi * 16);
                }
            }
        }

#pragma unroll
        for (int mi = 0; mi < 5; ++mi)
#pragma unroll
            for (int g = 0; g < 4; ++g) acc[mi][g] = (f32x4){0.f, 0.f, 0.f, 0.f};

        const char* hsb = smem + HS_OFF + (t & 1) * 10240;
        const char* hab = smem + HA_OFF + (t & 1) * 20480;
#pragma unroll
        for (int c = 0; c < 6; ++c) {
            const char* abase = (c < 2) ? (hsb + c * 5120) : (hab + (c - 2) * 5120);
            short8 a[5];
#pragma unroll
            for (int mi = 0; mi < 5; ++mi)
                a[mi] = *reinterpret_cast<const short8*>(abase + (mi * 16 + l15) * 64 + sw * 16);
#pragma unroll
            for (int g = 0; g < 4; ++g)
#pragma unroll
                for (int mi = 0; mi < 5; ++mi)
                    acc[mi][g] = __builtin_amdgcn_mfma_f32_16x16x32_bf16(a[mi], breg[c][g], acc[mi][g], 0, 0, 0);
        }

        // epilogue writes h into the OTHER slot -> no barrier needed before it
        char* hwr = smem + HA_OFF + ((t + 1) & 1) * 20480;
        if (t + 1 < TT) {
#pragma unroll
            for (int mi = 0; mi < 5; ++mi)
#pragma unroll
                for (int r = 0; r < 4; ++r) {
                    float iv = sigf(acc[mi][0][r] + bi);
                    float fv = sigf(acc[mi][1][r] + bff);
                    float gv = tanh_fast(acc[mi][2][r] + bg);
                    float ov = sigf(acc[mi][3][r] + bo);
                    float cnew = fv * c_reg[mi][r] + iv * gv;
                    c_reg[mi][r] = cnew;
                    float hv = ov * tanh_fast(cnew);
                    int row = mi * 16 + o * 4 + r;
                    int gs_h = h_g ^ ((row >> 1) & 3);
                    *(unsigned short*)(hwr + h_chunk * 5120 + row * 64 + gs_h * 16 + h_j * 2) = f2b_rn(hv);
                }
        } else {
            // final step: fuse FC.  partial = h * fc_w[col]; reduce over 16 cols via shfl, stash per wave.
#pragma unroll
            for (int mi = 0; mi < 5; ++mi)
#pragma unroll
                for (int r = 0; r < 4; ++r) {
                    float iv = sigf(acc[mi][0][r] + bi);
                    float fv = sigf(acc[mi][1][r] + bff);
                    float gv = tanh_fast(acc[mi][2][r] + bg);
                    float ov = sigf(acc[mi][3][r] + bo);
                    float cnew = fv * c_reg[mi][r] + iv * gv;
                    float hv = ov * tanh_fast(cnew);
                    float p = hv * fcw;
                    p += __shfl_xor(p, 1);
                    p += __shfl_xor(p, 2);
                    p += __shfl_xor(p, 4);
                    p += __shfl_xor(p, 8);
                    if (l15 == 0) {
                        int row = mi * 16 + o * 4 + r;
                        ((float*)(smem + RED_OFF))[w * 80 + row] = p;
                    }
                }
        }
        __syncthreads();  // single barrier: publishes h[t+1] writes + drains hs[t+1] staging
    }

    if (tid < 80) {
        const float* red = (const float*)(smem + RED_OFF);
        float s = 0.f;
#pragma unroll
        for (int w8 = 0; w8 < 8; ++w8) s += red[w8 * 80 + tid];
        out[base + tid] = s + fc_b[0];
    }
}

// ---------------- host ----------------

extern "C" void kernel_launch(void* const* d_in, const int* in_sizes, int n_in,
                              void* d_out, int out_size, void* d_ws, size_t ws_size,
                              hipStream_t stream) {
    const float* x_seq = (const float*)d_in[0];
    const int* edge = (const int*)d_in[1];
    const float* gcn_w = (const float*)d_in[2];
    const float* gcn_b = (const float*)d_in[3];
    const float* w_ih = (const float*)d_in[4];
    const float* w_hh = (const float*)d_in[5];
    const float* b_ih = (const float*)d_in[6];
    const float* b_hh = (const float*)d_in[7];
    const float* fc_w = (const float*)d_in[8];
    const float* fc_b = (const float*)d_in[9];
    float* out = (float*)d_out;

    char* w = (char*)d_ws;
    auto carve = [&](size_t bytes) {
        void* p = (void*)w;
        w += (bytes + 255) & ~(size_t)255;
        return p;
    };
    float* dinv = (float*)carve(NN * 4);
    int* deg = (int*)carve(NN * 4);
    int* row_ptr = (int*)carve((NN + 1) * 4);
    int* cursor = (int*)carve(NN * 4);
    int* csr_src = (int*)carve(NE * 4);
    float* csr_norm = (float*)carve(NE * 4);
    unsigned short* xwb = (unsigned short*)carve((size_t)TOTAL * GH * 2);
    unsigned short* hs_b = (unsigned short*)carve((size_t)TOTAL * GH * 2);
    unsigned short* wp = (unsigned short*)carve((size_t)6 * 512 * 4 * 8 * 2);
    unsigned short* wx = (unsigned short*)carve((size_t)4 * 64 * 4 * 8 * 2);
    float* bias = (float*)carve(512 * 4);

    hipMemsetAsync(deg, 0, NN * 4, stream);

    const int* e_src = edge;
    const int* e_dst = edge + NE;

    degree_kernel<<<(NE + 255) / 256, 256, 0, stream>>>(e_dst, deg);
    dinv_kernel<<<(NN + 255) / 256, 256, 0, stream>>>(deg, dinv);
    scan_kernel<<<1, 1024, 0, stream>>>(deg, row_ptr, cursor);
    scatter_kernel<<<(NE + 255) / 256, 256, 0, stream>>>(e_src, e_dst, dinv, cursor, csr_src, csr_norm);

    wprep_lstm_kernel<<<(6 * 512 * 4 + 255) / 256, 256, 0, stream>>>(w_ih, w_hh, wp);
    wprep_gcn_kernel<<<(4 * 64 * 4 + 255) / 256, 256, 0, stream>>>(gcn_w, wx);
    bias_kernel<<<2, 256, 0, stream>>>(b_ih, b_hh, bias);

    xw_mfma_kernel<<<TOTAL / 64, 256, 0, stream>>>(x_seq, wx, xwb);
    dim3 ggrid(NN / 2 / 4, TT / 2);
    gather_kernel<<<ggrid, 256, 0, stream>>>(xwb, dinv, row_ptr, csr_src, csr_norm, gcn_b, hs_b);
    lstm_persist_kernel<<<NN / 80, 512, 0, stream>>>(hs_b, wp, bias, fc_w, fc_b, out);
}